// Round 11
// baseline (93.709 us; speedup 1.0000x reference)
//
#include <hip/hip_runtime.h>
#include <math.h>

#define N_TOK 8192
#define DIM   256
#define INV_T 14.285714285714286f
#define RANGE 14.2857142857f
#define EPS   1e-8f
#define NBINS 8192
#define LOG2E 1.44269504f
#define CE    (INV_T * LOG2E)
#define SCALE_F 4.539816f              // sqrt(INV_T*LOG2E): dot(Pq,Pq) = sim*INV_T*LOG2E

typedef __attribute__((ext_vector_type(4))) float f32x4;

// workspace layout (bytes)
#define OFF_P     0
#define P_BYTES   (N_TOK * DIM)                // 2 MB fp8 normalized+scaled feats
#define OFF_PP    (OFF_P + P_BYTES)            // 2 MB pos partials [64][8192]
#define OFF_PN    (OFF_PP + 64 * N_TOK * 4)    // 2 MB neg partials
#define OFF_HIST  (OFF_PN + 64 * N_TOK * 4)
#define OFF_THR   (OFF_HIST + NBINS * 4)       // thr @ +0, acc[3] @ +16

#define GLOBAL_AS __attribute__((address_space(1)))
#define LDS_AS    __attribute__((address_space(3)))

#define ROWB 272                               // fp8 full-K row: 17 x 16B (pad)
#define SLOTS_PER_MAT (128 * 17)               // 2176 16B slots per matrix
#define STAGE_CALLS (2 * SLOTS_PER_MAT / 64)   // 68 wave-calls total

// triangular decode: linear b -> (it, jt) with jt >= it, 64x64 tile grid
__device__ __forceinline__ void tri_decode(int b, int& it, int& jt) {
    int i_low = (int)((sqrtf(8.f * (float)b + 1.f) - 1.f) * 0.5f);
    while ((i_low + 1) * (i_low + 2) / 2 <= b) ++i_low;
    while (i_low * (i_low + 1) / 2 > b) --i_low;
    const int j_low = b - i_low * (i_low + 1) / 2;
    it = 63 - i_low; jt = 63 - j_low;
}

// ------------------------------------------------- normalize + fp8 (scaled)
__global__ __launch_bounds__(256) void k_prep(const float* __restrict__ feats,
                                              unsigned int* __restrict__ Pq) {
    const int row = blockIdx.x * 4 + (threadIdx.x >> 6);
    const int l = threadIdx.x & 63;
    const float4 v = *reinterpret_cast<const float4*>(&feats[(size_t)row * DIM + l * 4]);
    float s = v.x * v.x + v.y * v.y + v.z * v.z + v.w * v.w;
#pragma unroll
    for (int m = 1; m <= 32; m <<= 1) s += __shfl_xor(s, m);
    const float r = SCALE_F / fmaxf(sqrtf(s), EPS);
    int pk = __builtin_amdgcn_cvt_pk_fp8_f32(v.x * r, v.y * r, 0, false);
    pk = __builtin_amdgcn_cvt_pk_fp8_f32(v.z * r, v.w * r, pk, true);
    Pq[row * 64 + l] = (unsigned int)pk;
}

// ------------------------------------------------- shared: stage full-K + fp8 GEMM
// 512 threads / 8 waves; wave (wr,wc) computes 32x64 of the 128x128 tile.
// One barrier total; K-loop is pure ds_read_b64 + MFMA (immediate offsets).
__device__ __forceinline__ void stage_and_gemm(
    const char* __restrict__ Pq, int iBase, int jBase,
    char* At, char* Bt, int tid, f32x4 (&acc)[2][4]) {
    const int w = tid >> 6, l = tid & 63;
    for (int k = w; k < STAGE_CALLS; k += 8) {
        const int s0 = k * 64;                         // wave-uniform slot base
        const int isB = (s0 >= SLOTS_PER_MAT);         // uniform (2176 % 64 == 0)
        const int r0 = s0 - (isB ? SLOTS_PER_MAT : 0);
        const int sl = r0 + l;
        const int row = sl / 17;
        const int col = sl - row * 17;                 // 16 data slots + 1 pad
        const int gb = isB ? jBase : iBase;
        const char* src = Pq + (size_t)(gb + row) * DIM + (col & 15) * 16;
        char* dst = (isB ? Bt : At) + (size_t)r0 * 16; // linear dest, lane x 16B
        __builtin_amdgcn_global_load_lds((const GLOBAL_AS unsigned int*)src,
                                         (LDS_AS unsigned int*)dst, 16, 0, 0);
    }
    __syncthreads();   // single drain: all staging done

    const int wr = w >> 1, wc = w & 1;
    const int g = l >> 4, p = l & 15;
    const char* a0 = At + (wr * 32 + p) * ROWB + g * 8;
    const char* b0 = Bt + (wc * 64 + p) * ROWB + g * 8;
#pragma unroll
    for (int c = 0; c < 8; ++c) {                      // K = 256, 32 per chunk
        const int off = c * 32;
        const long af0 = *(const long*)(a0 + off);
        const long af1 = *(const long*)(a0 + 16 * ROWB + off);
        const long bf0 = *(const long*)(b0 + off);
        const long bf1 = *(const long*)(b0 + 16 * ROWB + off);
        const long bf2 = *(const long*)(b0 + 32 * ROWB + off);
        const long bf3 = *(const long*)(b0 + 48 * ROWB + off);
        acc[0][0] = __builtin_amdgcn_mfma_f32_16x16x32_fp8_fp8(af0, bf0, acc[0][0], 0, 0, 0);
        acc[0][1] = __builtin_amdgcn_mfma_f32_16x16x32_fp8_fp8(af0, bf1, acc[0][1], 0, 0, 0);
        acc[0][2] = __builtin_amdgcn_mfma_f32_16x16x32_fp8_fp8(af0, bf2, acc[0][2], 0, 0, 0);
        acc[0][3] = __builtin_amdgcn_mfma_f32_16x16x32_fp8_fp8(af0, bf3, acc[0][3], 0, 0, 0);
        acc[1][0] = __builtin_amdgcn_mfma_f32_16x16x32_fp8_fp8(af1, bf0, acc[1][0], 0, 0, 0);
        acc[1][1] = __builtin_amdgcn_mfma_f32_16x16x32_fp8_fp8(af1, bf1, acc[1][1], 0, 0, 0);
        acc[1][2] = __builtin_amdgcn_mfma_f32_16x16x32_fp8_fp8(af1, bf2, acc[1][2], 0, 0, 0);
        acc[1][3] = __builtin_amdgcn_mfma_f32_16x16x32_fp8_fp8(af1, bf3, acc[1][3], 0, 0, 0);
    }
}

// ------------------------------------------------- sampled histogram pass
// grid = 65 real blocks: every 32nd upper-tri tile; B in LDS, A row in regs.
__global__ __launch_bounds__(512, 2) void k_hist(
    const char* __restrict__ Pq, const int* __restrict__ did,
    unsigned int* __restrict__ hist) {
    int it, jt;
    tri_decode(blockIdx.x * 32, it, jt);
    const int iBase = it * 128, jBase = jt * 128;
    const bool diag = (it == jt);

    __shared__ __align__(16) char Bt[SLOTS_PER_MAT * 16];
    __shared__ int dA[128], dB[128];
    __shared__ unsigned int h[NBINS];          // 32 KB

    const int tid = threadIdx.x;
    const int w = tid >> 6, l = tid & 63;
    const int wr = w >> 1, wc = w & 1;
    const int g = l >> 4, p = l & 15;

    if (tid < 128) dA[tid] = did[iBase + tid];
    else if (tid < 256) dB[tid - 128] = did[jBase + tid - 128];
    for (int i = tid; i < NBINS; i += 512) h[i] = 0;

    // A fragment (fm=0 row only) direct to registers from L2
    long aReg[8];
    {
        const char* a0 = Pq + (size_t)(iBase + wr * 32 + p) * DIM + g * 8;
#pragma unroll
        for (int c = 0; c < 8; ++c) aReg[c] = *(const long*)(a0 + c * 32);
    }
    for (int k = w; k < 34; k += 8) {
        const int slot = k * 64 + l;
        const int row = slot / 17, sIdx = slot - row * 17;
        const char* src = Pq + (size_t)(jBase + row) * 256 + (sIdx & 15) * 16;
        __builtin_amdgcn_global_load_lds((const GLOBAL_AS unsigned int*)src,
                                         (LDS_AS unsigned int*)(Bt + k * 1024), 16, 0, 0);
    }
    __syncthreads();

    f32x4 acc0[4];
#pragma unroll
    for (int c = 0; c < 4; c++) acc0[c] = (f32x4){0.f, 0.f, 0.f, 0.f};
    const char* b0 = Bt + (wc * 64 + p) * ROWB + g * 8;
#pragma unroll
    for (int c = 0; c < 8; ++c) {
        const int off = c * 32;
        const long bf0 = *(const long*)(b0 + off);
        const long bf1 = *(const long*)(b0 + 16 * ROWB + off);
        const long bf2 = *(const long*)(b0 + 32 * ROWB + off);
        const long bf3 = *(const long*)(b0 + 48 * ROWB + off);
        acc0[0] = __builtin_amdgcn_mfma_f32_16x16x32_fp8_fp8(aReg[c], bf0, acc0[0], 0, 0, 0);
        acc0[1] = __builtin_amdgcn_mfma_f32_16x16x32_fp8_fp8(aReg[c], bf1, acc0[1], 0, 0, 0);
        acc0[2] = __builtin_amdgcn_mfma_f32_16x16x32_fp8_fp8(aReg[c], bf2, acc0[2], 0, 0, 0);
        acc0[3] = __builtin_amdgcn_mfma_f32_16x16x32_fp8_fp8(aReg[c], bf3, acc0[3], 0, 0, 0);
    }

    int dRow[4];
#pragma unroll
    for (int q = 0; q < 4; ++q) dRow[q] = dA[wr * 32 + g * 4 + q];

    const unsigned int wgt = diag ? 1u : 2u;
    // acc is tt-units (sim*INV_T*LOG2E); bin on s = tt/LOG2E
    const float K1H = ((float)NBINS / (2.0f * RANGE)) / LOG2E;
    const float K0 = 0.5f * (float)NBINS;
#pragma unroll
    for (int fn = 0; fn < 4; ++fn) {
        const int dcol = dB[wc * 64 + fn * 16 + p];
#pragma unroll
        for (int q = 0; q < 4; ++q) {
            if (dRow[q] != dcol) {
                int bn = (int)fmaf(acc0[fn][q], K1H, K0);
                bn = min(max(bn, 0), NBINS - 1);
                atomicAdd(&h[bn], wgt);
            }
        }
    }
    __syncthreads();
    for (int i = tid; i < NBINS; i += 512) {
        unsigned int c = h[i];
        if (c) atomicAdd(&hist[i], c);
    }
}

// ------------------------------------------------- main pass (all upper-tri)
// A+B full-K in LDS (77.8 KB -> 2 blocks/CU), bounds (512,4) [empirical best].
__global__ __launch_bounds__(512, 4) void k_main(
    const char* __restrict__ Pq,
    const int* __restrict__ did, const int* __restrict__ iid,
    const float* __restrict__ thrp,
    float* __restrict__ partP, float* __restrict__ partN) {
    int it, jt;
    tri_decode(blockIdx.x, it, jt);
    const int iBase = it * 128, jBase = jt * 128;
    const bool diag = (it == jt);

    __shared__ __align__(16) char At[SLOTS_PER_MAT * 16];
    __shared__ __align__(16) char Bt[SLOTS_PER_MAT * 16];
    __shared__ int dA[128], kA[128], dB[128], kB[128];

    const int tid = threadIdx.x;
    const int w = tid >> 6, l = tid & 63;
    const int wr = w >> 1, wc = w & 1;          // wave -> 32-row x 64-col sub-tile
    const int g = l >> 4, p = l & 15;

    if (tid < 128) {
        int d = did[iBase + tid], i2 = iid[iBase + tid];
        dA[tid] = d; kA[tid] = (d << 16) | i2;
    } else if (tid < 256) {
        int r = tid - 128;
        int d = did[jBase + r], i2 = iid[jBase + r];
        dB[r] = d; kB[r] = (d << 16) | i2;
    }

    f32x4 acc[2][4];
#pragma unroll
    for (int a = 0; a < 2; a++)
#pragma unroll
        for (int c = 0; c < 4; c++) acc[a][c] = (f32x4){0.f, 0.f, 0.f, 0.f};

    stage_and_gemm(Pq, iBase, jBase, At, Bt, tid, acc);
    __syncthreads();   // all waves done reading Bt -> safe to alias reduce buffers

    // C/D layout (m89-verified): col = lane&15, row = (lane>>4)*4 + reg
    int dRow[2][4], kRow[2][4];
#pragma unroll
    for (int fm = 0; fm < 2; ++fm)
#pragma unroll
        for (int q = 0; q < 4; ++q) {
            const int rIdx = wr * 32 + fm * 16 + g * 4 + q;
            dRow[fm][q] = dA[rIdx];
            kRow[fm][q] = kA[rIdx];
        }

    // acc IS tt = s*log2e (scale folded in prep). T = sum e*wg; P = sum e pos.
    const float thr2 = thrp[0] * LOG2E;
    const float E_DIAG = __builtin_amdgcn_exp2f(CE);
    float tR[2][4], pR[2][4], tC[4], pC[4];
#pragma unroll
    for (int a = 0; a < 4; a++) { tC[a] = 0.f; pC[a] = 0.f; }
#pragma unroll
    for (int a = 0; a < 2; a++)
#pragma unroll
        for (int c = 0; c < 4; c++) { tR[a][c] = 0.f; pR[a][c] = 0.f; }

    if (!diag) {   // 2016/2080 blocks: no self-pair logic
#pragma unroll
        for (int fn = 0; fn < 4; ++fn) {
            const int cIdx = wc * 64 + fn * 16 + p;
            const int dcol = dB[cIdx], kcol = kB[cIdx];
#pragma unroll
            for (int fm = 0; fm < 2; ++fm)
#pragma unroll
                for (int q = 0; q < 4; ++q) {
                    const float tt = acc[fm][fn][q];
                    const float e = __builtin_amdgcn_exp2f(tt);
                    const float w1 = (tt > thr2) ? 3.0f : 1.5f;
                    const float wg = (dRow[fm][q] != dcol) ? w1 : 1.0f;
                    tR[fm][q] = fmaf(e, wg, tR[fm][q]);
                    tC[fn] = fmaf(e, wg, tC[fn]);
                    const float ep = (kRow[fm][q] == kcol) ? e : 0.f;
                    pR[fm][q] += ep;
                    pC[fn] += ep;
                }
        }
    } else {
#pragma unroll
        for (int fn = 0; fn < 4; ++fn) {
            const int cIdx = wc * 64 + fn * 16 + p;
            const int dcol = dB[cIdx], kcol = kB[cIdx];
#pragma unroll
            for (int fm = 0; fm < 2; ++fm)
#pragma unroll
                for (int q = 0; q < 4; ++q) {
                    const int rIdx = wr * 32 + fm * 16 + g * 4 + q;
                    const float tt = acc[fm][fn][q];
                    float e = __builtin_amdgcn_exp2f(tt);
                    const bool self = (rIdx == cIdx);
                    e = self ? E_DIAG : e;
                    const float w1 = (tt > thr2) ? 3.0f : 1.5f;
                    const float wg = (dRow[fm][q] != dcol) ? w1 : 1.0f;
                    tR[fm][q] = fmaf(e, wg, tR[fm][q]);
                    tC[fn] = fmaf(e, wg, tC[fn]);
                    const float ep = ((kRow[fm][q] == kcol) && !self) ? e : 0.f;
                    pR[fm][q] += ep;
                    pC[fn] += ep;
                }
        }
    }
    // ---- row sums: reduce across the 16-lane column groups
#pragma unroll
    for (int m = 1; m <= 8; m <<= 1)
#pragma unroll
        for (int a = 0; a < 2; a++)
#pragma unroll
            for (int c = 0; c < 4; c++) {
                tR[a][c] += __shfl_xor(tR[a][c], m);
                pR[a][c] += __shfl_xor(pR[a][c], m);
            }
    // ---- col sums: reduce across the 4 row groups
#pragma unroll
    for (int m = 16; m <= 32; m <<= 1)
#pragma unroll
        for (int a = 0; a < 4; a++) {
            tC[a] += __shfl_xor(tC[a], m);
            pC[a] += __shfl_xor(pC[a], m);
        }
    float tv = 0.f, pv = 0.f;
#pragma unroll
    for (int fm = 0; fm < 2; ++fm)
#pragma unroll
        for (int q = 0; q < 4; ++q)
            if (p == fm * 4 + q) { tv = tR[fm][q]; pv = pR[fm][q]; }

    // reduce buffers aliased onto dead Bt
    float* rbT = (float*)Bt;           // [2][128]
    float* rbP = rbT + 256;            // [2][128]
    float* cbT = rbP + 256;            // [4][128]
    float* cbP = cbT + 512;            // [4][128]
    if (p < 8) {
        const int rowLocal = (p >> 2) * 16 + g * 4 + (p & 3);
        rbT[wc * 128 + wr * 32 + rowLocal] = tv;
        rbP[wc * 128 + wr * 32 + rowLocal] = pv;
    }
    if (l < 16) {
#pragma unroll
        for (int fn = 0; fn < 4; ++fn) {
            cbT[wr * 128 + wc * 64 + fn * 16 + l] = tC[fn];
            cbP[wr * 128 + wc * 64 + fn * 16 + l] = pC[fn];
        }
    }
    __syncthreads();
    if (tid < 128) {
        const float T = rbT[tid] + rbT[128 + tid];
        const float Pp = rbP[tid] + rbP[128 + tid];
        const size_t off = (size_t)jt * N_TOK + iBase + tid;
        partP[off] = Pp;
        partN[off] = T - Pp;
    } else if (tid < 256 && !diag) {
        const int c = tid - 128;
        const float T = cbT[c] + cbT[128 + c] + cbT[256 + c] + cbT[384 + c];
        const float Pp = cbP[c] + cbP[128 + c] + cbP[256 + c] + cbP[384 + c];
        const size_t off = (size_t)it * N_TOK + jBase + c;
        partP[off] = Pp;
        partN[off] = T - Pp;
    }
}

// ---------------------------------------------------------------- quantile
__global__ __launch_bounds__(1024) void k_thr(const unsigned int* __restrict__ hist,
                                              float* __restrict__ thrp) {
    __shared__ unsigned long long scan[1024];
    const int t = threadIdx.x;
    const int CHUNK = NBINS / 1024;  // 8
    const int base = t * CHUNK;
    unsigned long long own = 0;
    for (int i = 0; i < CHUNK; i++) own += hist[base + i];
    scan[t] = own;
    __syncthreads();
    for (int o = 1; o < 1024; o <<= 1) {
        unsigned long long v = (t >= o) ? scan[t - o] : 0ULL;
        __syncthreads();
        scan[t] += v;
        __syncthreads();
    }
    unsigned long long total = scan[1023];
    if (total == 0) {
        if (t == 0) thrp[0] = 0.f;
        return;
    }
    unsigned long long k1 = (4ULL * (total - 1)) / 5ULL;   // floor(0.8*(n-1)) exact
    unsigned long long rem = (4ULL * (total - 1)) % 5ULL;
    float frac = (float)rem * 0.2f;
    unsigned long long k2 = (k1 + 1 < total) ? k1 + 1 : k1;
    __shared__ float vk[2];
    unsigned long long cumBefore = scan[t] - own;
    const float binw = 2.0f * RANGE / (float)NBINS;
    for (int which = 0; which < 2; which++) {
        unsigned long long k = which ? k2 : k1;
        if (cumBefore <= k && k < scan[t]) {
            unsigned long long c = cumBefore;
            int bin = base;
            for (int i = 0; i < CHUNK; i++) {
                c += hist[base + i];
                if (c > k) { bin = base + i; break; }
            }
            vk[which] = -RANGE + ((float)bin + 0.5f) * binw;
        }
    }
    __syncthreads();
    if (t == 0) thrp[0] = vk[0] + frac * (vk[1] - vk[0]);
}

// ---------------------------------------------------------------- reduce
__global__ __launch_bounds__(256) void k_reduce(const float* __restrict__ pp,
                                                const float* __restrict__ pn,
                                                float* __restrict__ acc) {
    const int t = threadIdx.x;
    const int r = blockIdx.x * 128 + (t & 127);
    const int jh = t >> 7;
    float sp = 0.f, sn = 0.f;
    const float* bp = pp + (size_t)jh * 32 * N_TOK + r;
    const float* bn = pn + (size_t)jh * 32 * N_TOK + r;
#pragma unroll 8
    for (int j = 0; j < 32; ++j) {
        sp += bp[(size_t)j * N_TOK];
        sn += bn[(size_t)j * N_TOK];
    }
    __shared__ float shp[128], shn[128];
    if (jh) { shp[t & 127] = sp; shn[t & 127] = sn; }
    __syncthreads();
    float sumV = 0.f, sumA = 0.f, cnt = 0.f;
    if (!jh) {
        const float p = sp + shp[t];
        const float n = sn + shn[t];
        const float loss = -logf((p + EPS) / (p + n + EPS));
        sumA = loss;
        if (p > 0.f) { sumV = loss; cnt = 1.f; }
    }
#pragma unroll
    for (int m = 1; m <= 32; m <<= 1) {
        sumV += __shfl_xor(sumV, m);
        sumA += __shfl_xor(sumA, m);
        cnt += __shfl_xor(cnt, m);
    }
    __shared__ float wv[4], wa[4], wn[4];
    if ((t & 63) == 0) { wv[t >> 6] = sumV; wa[t >> 6] = sumA; wn[t >> 6] = cnt; }
    __syncthreads();
    if (t == 0) {
        atomicAdd(&acc[0], wv[0] + wv[1] + wv[2] + wv[3]);
        atomicAdd(&acc[1], wa[0] + wa[1] + wa[2] + wa[3]);
        atomicAdd(&acc[2], wn[0] + wn[1] + wn[2] + wn[3]);
    }
}

__global__ __launch_bounds__(64) void k_last(const float* __restrict__ acc,
                                             float* __restrict__ out) {
    if (threadIdx.x == 0) {
        const float nv = acc[2];
        out[0] = (nv > 0.f) ? (acc[0] / fmaxf(nv, 1.f)) : (acc[1] / (float)N_TOK);
    }
}

// ---------------------------------------------------------------- launch
extern "C" void kernel_launch(void* const* d_in, const int* in_sizes, int n_in,
                              void* d_out, int out_size, void* d_ws, size_t ws_size,
                              hipStream_t stream) {
    (void)in_sizes; (void)n_in; (void)out_size; (void)ws_size;
    const float* feats = (const float*)d_in[0];
    const int* did = (const int*)d_in[1];
    const int* iid = (const int*)d_in[2];
    char* ws = (char*)d_ws;
    char* Pq = ws + OFF_P;
    float* partP = (float*)(ws + OFF_PP);
    float* partN = (float*)(ws + OFF_PN);
    unsigned int* hist = (unsigned int*)(ws + OFF_HIST);
    float* thrp = (float*)(ws + OFF_THR);
    float* accum = (float*)(ws + OFF_THR + 16);

    hipMemsetAsync(ws + OFF_HIST, 0, NBINS * 4 + 256, stream);
    k_prep<<<N_TOK / 4, 256, 0, stream>>>(feats, (unsigned int*)Pq);
    k_hist<<<65, 512, 0, stream>>>(Pq, did, hist);
    k_thr<<<1, 1024, 0, stream>>>(hist, thrp);
    k_main<<<64 * 65 / 2, 512, 0, stream>>>(Pq, did, iid, thrp, partP, partN);
    k_reduce<<<64, 256, 0, stream>>>(partP, partN, accum);
    k_last<<<1, 64, 0, stream>>>(accum, (float*)d_out);
}

// Round 12
// 68.976 us; speedup vs baseline: 1.3586x; 1.3586x over previous
//
#include <hip/hip_runtime.h>
#include <math.h>

#define N_TOK 8192
#define DIM   256
#define INV_T 14.285714285714286f
#define RANGE 14.2857142857f
#define EPS   1e-8f
#define NBINS 8192
#define LOG2E 1.44269504f

typedef __attribute__((ext_vector_type(4))) float f32x4;

// workspace layout (bytes)
#define OFF_P     0
#define P_BYTES   (N_TOK * DIM)                // 2 MB fp8 normalized feats
#define OFF_PP    (OFF_P + P_BYTES)            // 2 MB pos partials [64][8192]
#define OFF_PN    (OFF_PP + 64 * N_TOK * 4)    // 2 MB neg partials
#define OFF_HIST  (OFF_PN + 64 * N_TOK * 4)
#define OFF_THR   (OFF_HIST + NBINS * 4)       // thr @ +0, acc[3] @ +16

#define GLOBAL_AS __attribute__((address_space(1)))
#define LDS_AS    __attribute__((address_space(3)))

#define ROWB 272                               // fp8 full-K row: 17 x 16B (pad)
#define SLOTS_PER_MAT (128 * 17)               // 2176 16B slots per matrix
#define STAGE_CALLS (2 * SLOTS_PER_MAT / 64)   // 68 wave-calls total

// triangular decode: linear b -> (it, jt) with jt >= it, 64x64 tile grid
__device__ __forceinline__ void tri_decode(int b, int& it, int& jt) {
    int i_low = (int)((sqrtf(8.f * (float)b + 1.f) - 1.f) * 0.5f);
    while ((i_low + 1) * (i_low + 2) / 2 <= b) ++i_low;
    while (i_low * (i_low + 1) / 2 > b) --i_low;
    const int j_low = b - i_low * (i_low + 1) / 2;
    it = 63 - i_low; jt = 63 - j_low;
}

// ------------------------------------------------- normalize + fp8 convert
// also zeroes hist (blocks 0..31) and accum (block 32) -> no memset launch
__global__ __launch_bounds__(256) void k_prep(const float* __restrict__ feats,
                                              unsigned int* __restrict__ Pq,
                                              unsigned int* __restrict__ hist,
                                              float* __restrict__ accum) {
    if (blockIdx.x < 32) hist[blockIdx.x * 256 + threadIdx.x] = 0u;
    else if (blockIdx.x == 32 && threadIdx.x < 4) accum[threadIdx.x] = 0.f;
    const int row = blockIdx.x * 4 + (threadIdx.x >> 6);
    const int l = threadIdx.x & 63;
    const float4 v = *reinterpret_cast<const float4*>(&feats[(size_t)row * DIM + l * 4]);
    float s = v.x * v.x + v.y * v.y + v.z * v.z + v.w * v.w;
#pragma unroll
    for (int m = 1; m <= 32; m <<= 1) s += __shfl_xor(s, m);
    const float r = 1.0f / fmaxf(sqrtf(s), EPS);
    int pk = __builtin_amdgcn_cvt_pk_fp8_f32(v.x * r, v.y * r, 0, false);
    pk = __builtin_amdgcn_cvt_pk_fp8_f32(v.z * r, v.w * r, pk, true);
    Pq[row * 64 + l] = (unsigned int)pk;
}

// ------------------------------------------------- shared: stage full-K + fp8 GEMM
// 512 threads / 8 waves; wave (wr,wc) computes 32x64 of the 128x128 tile.
// One barrier total; K-loop is pure ds_read_b64 + MFMA (immediate offsets).
__device__ __forceinline__ void stage_and_gemm(
    const char* __restrict__ Pq, int iBase, int jBase,
    char* At, char* Bt, int tid, f32x4 (&acc)[2][4]) {
    const int w = tid >> 6, l = tid & 63;
    for (int k = w; k < STAGE_CALLS; k += 8) {
        const int s0 = k * 64;                         // wave-uniform slot base
        const int isB = (s0 >= SLOTS_PER_MAT);         // uniform (2176 % 64 == 0)
        const int r0 = s0 - (isB ? SLOTS_PER_MAT : 0);
        const int sl = r0 + l;
        const int row = sl / 17;
        const int col = sl - row * 17;                 // 16 data slots + 1 pad
        const int gb = isB ? jBase : iBase;
        const char* src = Pq + (size_t)(gb + row) * DIM + (col & 15) * 16;
        char* dst = (isB ? Bt : At) + (size_t)r0 * 16; // linear dest, lane x 16B
        __builtin_amdgcn_global_load_lds((const GLOBAL_AS unsigned int*)src,
                                         (LDS_AS unsigned int*)dst, 16, 0, 0);
    }
    __syncthreads();   // single drain: all staging done

    const int wr = w >> 1, wc = w & 1;
    const int g = l >> 4, p = l & 15;
    const char* a0 = At + (wr * 32 + p) * ROWB + g * 8;
    const char* b0 = Bt + (wc * 64 + p) * ROWB + g * 8;
#pragma unroll
    for (int c = 0; c < 8; ++c) {                      // K = 256, 32 per chunk
        const int off = c * 32;
        const long af0 = *(const long*)(a0 + off);
        const long af1 = *(const long*)(a0 + 16 * ROWB + off);
        const long bf0 = *(const long*)(b0 + off);
        const long bf1 = *(const long*)(b0 + 16 * ROWB + off);
        const long bf2 = *(const long*)(b0 + 32 * ROWB + off);
        const long bf3 = *(const long*)(b0 + 48 * ROWB + off);
        acc[0][0] = __builtin_amdgcn_mfma_f32_16x16x32_fp8_fp8(af0, bf0, acc[0][0], 0, 0, 0);
        acc[0][1] = __builtin_amdgcn_mfma_f32_16x16x32_fp8_fp8(af0, bf1, acc[0][1], 0, 0, 0);
        acc[0][2] = __builtin_amdgcn_mfma_f32_16x16x32_fp8_fp8(af0, bf2, acc[0][2], 0, 0, 0);
        acc[0][3] = __builtin_amdgcn_mfma_f32_16x16x32_fp8_fp8(af0, bf3, acc[0][3], 0, 0, 0);
        acc[1][0] = __builtin_amdgcn_mfma_f32_16x16x32_fp8_fp8(af1, bf0, acc[1][0], 0, 0, 0);
        acc[1][1] = __builtin_amdgcn_mfma_f32_16x16x32_fp8_fp8(af1, bf1, acc[1][1], 0, 0, 0);
        acc[1][2] = __builtin_amdgcn_mfma_f32_16x16x32_fp8_fp8(af1, bf2, acc[1][2], 0, 0, 0);
        acc[1][3] = __builtin_amdgcn_mfma_f32_16x16x32_fp8_fp8(af1, bf3, acc[1][3], 0, 0, 0);
    }
}

// ------------------------------------------------- sampled histogram pass
// grid = 65 real blocks: every 32nd upper-tri tile; B in LDS, A (fm=0) in regs.
__global__ __launch_bounds__(512, 2) void k_hist(
    const char* __restrict__ Pq, const int* __restrict__ did,
    unsigned int* __restrict__ hist) {
    int it, jt;
    tri_decode(blockIdx.x * 32, it, jt);
    const int iBase = it * 128, jBase = jt * 128;
    const bool diag = (it == jt);

    __shared__ __align__(16) char Bt[SLOTS_PER_MAT * 16];
    __shared__ int dA[128], dB[128];
    __shared__ unsigned int h[NBINS];          // 32 KB

    const int tid = threadIdx.x;
    const int w = tid >> 6, l = tid & 63;
    const int wr = w >> 1, wc = w & 1;
    const int g = l >> 4, p = l & 15;

    if (tid < 128) dA[tid] = did[iBase + tid];
    else if (tid < 256) dB[tid - 128] = did[jBase + tid - 128];
    for (int i = tid; i < NBINS; i += 512) h[i] = 0;

    // A fragment (fm=0 row only) direct to registers from L2
    long aReg[8];
    {
        const char* a0 = Pq + (size_t)(iBase + wr * 32 + p) * DIM + g * 8;
#pragma unroll
        for (int c = 0; c < 8; ++c) aReg[c] = *(const long*)(a0 + c * 32);
    }
    for (int k = w; k < 34; k += 8) {
        const int slot = k * 64 + l;
        const int row = slot / 17, sIdx = slot - row * 17;
        const char* src = Pq + (size_t)(jBase + row) * 256 + (sIdx & 15) * 16;
        __builtin_amdgcn_global_load_lds((const GLOBAL_AS unsigned int*)src,
                                         (LDS_AS unsigned int*)(Bt + k * 1024), 16, 0, 0);
    }
    __syncthreads();

    f32x4 acc0[4];
#pragma unroll
    for (int c = 0; c < 4; c++) acc0[c] = (f32x4){0.f, 0.f, 0.f, 0.f};
    const char* b0 = Bt + (wc * 64 + p) * ROWB + g * 8;
#pragma unroll
    for (int c = 0; c < 8; ++c) {
        const int off = c * 32;
        const long bf0 = *(const long*)(b0 + off);
        const long bf1 = *(const long*)(b0 + 16 * ROWB + off);
        const long bf2 = *(const long*)(b0 + 32 * ROWB + off);
        const long bf3 = *(const long*)(b0 + 48 * ROWB + off);
        acc0[0] = __builtin_amdgcn_mfma_f32_16x16x32_fp8_fp8(aReg[c], bf0, acc0[0], 0, 0, 0);
        acc0[1] = __builtin_amdgcn_mfma_f32_16x16x32_fp8_fp8(aReg[c], bf1, acc0[1], 0, 0, 0);
        acc0[2] = __builtin_amdgcn_mfma_f32_16x16x32_fp8_fp8(aReg[c], bf2, acc0[2], 0, 0, 0);
        acc0[3] = __builtin_amdgcn_mfma_f32_16x16x32_fp8_fp8(aReg[c], bf3, acc0[3], 0, 0, 0);
    }

    int dRow[4];
#pragma unroll
    for (int q = 0; q < 4; ++q) dRow[q] = dA[wr * 32 + g * 4 + q];

    const unsigned int wgt = diag ? 1u : 2u;
    const float binScale = (float)NBINS / (2.0f * RANGE);
    const float K1 = INV_T * binScale, K0 = RANGE * binScale;   // acc = sim
#pragma unroll
    for (int fn = 0; fn < 4; ++fn) {
        const int dcol = dB[wc * 64 + fn * 16 + p];
#pragma unroll
        for (int q = 0; q < 4; ++q) {
            if (dRow[q] != dcol) {
                int bn = (int)fmaf(acc0[fn][q], K1, K0);
                bn = min(max(bn, 0), NBINS - 1);
                atomicAdd(&h[bn], wgt);
            }
        }
    }
    __syncthreads();
    for (int i = tid; i < NBINS; i += 512) {
        unsigned int c = h[i];
        if (c) atomicAdd(&hist[i], c);
    }
}

// ------------------------------------------------- main pass (all upper-tri)
// FROZEN at the R7-measured optimum (44.5 us, VGPR 64, no spill). Do not touch.
__global__ __launch_bounds__(512, 4) void k_main(
    const char* __restrict__ Pq,
    const int* __restrict__ did, const int* __restrict__ iid,
    const float* __restrict__ thrp,
    float* __restrict__ partP, float* __restrict__ partN) {
    int it, jt;
    tri_decode(blockIdx.x, it, jt);
    const int iBase = it * 128, jBase = jt * 128;
    const bool diag = (it == jt);

    __shared__ __align__(16) char At[SLOTS_PER_MAT * 16];
    __shared__ __align__(16) char Bt[SLOTS_PER_MAT * 16];
    __shared__ int dA[128], kA[128], dB[128], kB[128];
    __shared__ float rbT[2][128], rbP[2][128];
    __shared__ float cbT[4][128], cbP[4][128];

    const int tid = threadIdx.x;
    const int w = tid >> 6, l = tid & 63;
    const int wr = w >> 1, wc = w & 1;          // wave -> 32-row x 64-col sub-tile
    const int g = l >> 4, p = l & 15;

    if (tid < 128) {
        int d = did[iBase + tid], i2 = iid[iBase + tid];
        dA[tid] = d; kA[tid] = (d << 16) | i2;
    } else if (tid < 256) {
        int r = tid - 128;
        int d = did[jBase + r], i2 = iid[jBase + r];
        dB[r] = d; kB[r] = (d << 16) | i2;
    }

    f32x4 acc[2][4];
#pragma unroll
    for (int a = 0; a < 2; a++)
#pragma unroll
        for (int c = 0; c < 4; c++) acc[a][c] = (f32x4){0.f, 0.f, 0.f, 0.f};

    stage_and_gemm(Pq, iBase, jBase, At, Bt, tid, acc);

    // C/D layout (m89-verified): col = lane&15, row = (lane>>4)*4 + reg
    int dRow[2][4], kRow[2][4], selfRow[2][4];
#pragma unroll
    for (int fm = 0; fm < 2; ++fm)
#pragma unroll
        for (int q = 0; q < 4; ++q) {
            const int rIdx = wr * 32 + fm * 16 + g * 4 + q;
            dRow[fm][q] = dA[rIdx];
            kRow[fm][q] = kA[rIdx];
            selfRow[fm][q] = diag ? rIdx : -1;
        }

    // T = sum e*wg over ALL entries; P = sum e over positives; N = T - P.
    // Self-pairs use the EXACT diag value exp(1/T) (fp8 |x|^2 error would be ~20%).
    const float CE = INV_T * LOG2E;
    const float thr2 = thrp[0] * LOG2E;
    const float E_DIAG = __builtin_amdgcn_exp2f(CE);   // exp(1/0.07), sim_ii == 1
    float tR[2][4], pR[2][4], tC[4], pC[4];
#pragma unroll
    for (int a = 0; a < 4; a++) { tC[a] = 0.f; pC[a] = 0.f; }
#pragma unroll
    for (int a = 0; a < 2; a++)
#pragma unroll
        for (int c = 0; c < 4; c++) { tR[a][c] = 0.f; pR[a][c] = 0.f; }

#pragma unroll
    for (int fn = 0; fn < 4; ++fn) {
        const int cIdx = wc * 64 + fn * 16 + p;
        const int dcol = dB[cIdx], kcol = kB[cIdx];
#pragma unroll
        for (int fm = 0; fm < 2; ++fm)
#pragma unroll
            for (int q = 0; q < 4; ++q) {
                const float tt = acc[fm][fn][q] * CE;
                float e = __builtin_amdgcn_exp2f(tt);
                const bool self = (selfRow[fm][q] == cIdx);
                e = self ? E_DIAG : e;
                const float w1 = (tt > thr2) ? 3.0f : 1.5f;
                const float wg = (dRow[fm][q] != dcol) ? w1 : 1.0f;
                tR[fm][q] = fmaf(e, wg, tR[fm][q]);
                tC[fn] = fmaf(e, wg, tC[fn]);
                const bool pos = (kRow[fm][q] == kcol) && !self;
                const float ep = pos ? e : 0.f;
                pR[fm][q] += ep;
                pC[fn] += ep;
            }
    }
    // ---- row sums: reduce across the 16-lane column groups
#pragma unroll
    for (int m = 1; m <= 8; m <<= 1)
#pragma unroll
        for (int a = 0; a < 2; a++)
#pragma unroll
            for (int c = 0; c < 4; c++) {
                tR[a][c] += __shfl_xor(tR[a][c], m);
                pR[a][c] += __shfl_xor(pR[a][c], m);
            }
    // ---- col sums: reduce across the 4 row groups
#pragma unroll
    for (int m = 16; m <= 32; m <<= 1)
#pragma unroll
        for (int a = 0; a < 4; a++) {
            tC[a] += __shfl_xor(tC[a], m);
            pC[a] += __shfl_xor(pC[a], m);
        }
    float tv = 0.f, pv = 0.f;
#pragma unroll
    for (int fm = 0; fm < 2; ++fm)
#pragma unroll
        for (int q = 0; q < 4; ++q)
            if (p == fm * 4 + q) { tv = tR[fm][q]; pv = pR[fm][q]; }

    if (p < 8) {
        const int rowLocal = (p >> 2) * 16 + g * 4 + (p & 3);
        rbT[wc][wr * 32 + rowLocal] = tv;
        rbP[wc][wr * 32 + rowLocal] = pv;
    }
    if (l < 16) {
#pragma unroll
        for (int fn = 0; fn < 4; ++fn) {
            cbT[wr][wc * 64 + fn * 16 + l] = tC[fn];
            cbP[wr][wc * 64 + fn * 16 + l] = pC[fn];
        }
    }
    __syncthreads();
    if (tid < 128) {
        const float T = rbT[0][tid] + rbT[1][tid];
        const float Pp = rbP[0][tid] + rbP[1][tid];
        const size_t off = (size_t)jt * N_TOK + iBase + tid;
        partP[off] = Pp;
        partN[off] = T - Pp;
    } else if (tid < 256 && !diag) {
        const int c = tid - 128;
        const float T = cbT[0][c] + cbT[1][c] + cbT[2][c] + cbT[3][c];
        const float Pp = cbP[0][c] + cbP[1][c] + cbP[2][c] + cbP[3][c];
        const size_t off = (size_t)it * N_TOK + jBase + c;
        partP[off] = Pp;
        partN[off] = T - Pp;
    }
}

// ---------------------------------------------------------------- quantile
__global__ __launch_bounds__(1024) void k_thr(const unsigned int* __restrict__ hist,
                                              float* __restrict__ thrp) {
    __shared__ unsigned long long scan[1024];
    const int t = threadIdx.x;
    const int CHUNK = NBINS / 1024;  // 8
    const int base = t * CHUNK;
    unsigned long long own = 0;
    for (int i = 0; i < CHUNK; i++) own += hist[base + i];
    scan[t] = own;
    __syncthreads();
    for (int o = 1; o < 1024; o <<= 1) {
        unsigned long long v = (t >= o) ? scan[t - o] : 0ULL;
        __syncthreads();
        scan[t] += v;
        __syncthreads();
    }
    unsigned long long total = scan[1023];
    if (total == 0) {
        if (t == 0) thrp[0] = 0.f;
        return;
    }
    unsigned long long k1 = (4ULL * (total - 1)) / 5ULL;   // floor(0.8*(n-1)) exact
    unsigned long long rem = (4ULL * (total - 1)) % 5ULL;
    float frac = (float)rem * 0.2f;
    unsigned long long k2 = (k1 + 1 < total) ? k1 + 1 : k1;
    __shared__ float vk[2];
    unsigned long long cumBefore = scan[t] - own;
    const float binw = 2.0f * RANGE / (float)NBINS;
    for (int which = 0; which < 2; which++) {
        unsigned long long k = which ? k2 : k1;
        if (cumBefore <= k && k < scan[t]) {
            unsigned long long c = cumBefore;
            int bin = base;
            for (int i = 0; i < CHUNK; i++) {
                c += hist[base + i];
                if (c > k) { bin = base + i; break; }
            }
            vk[which] = -RANGE + ((float)bin + 0.5f) * binw;
        }
    }
    __syncthreads();
    if (t == 0) thrp[0] = vk[0] + frac * (vk[1] - vk[0]);
}

// ---------------------------------------------------------------- reduce
__global__ __launch_bounds__(256) void k_reduce(const float* __restrict__ pp,
                                                const float* __restrict__ pn,
                                                float* __restrict__ acc) {
    const int t = threadIdx.x;
    const int r = blockIdx.x * 128 + (t & 127);
    const int jh = t >> 7;
    float sp = 0.f, sn = 0.f;
    const float* bp = pp + (size_t)jh * 32 * N_TOK + r;
    const float* bn = pn + (size_t)jh * 32 * N_TOK + r;
#pragma unroll 8
    for (int j = 0; j < 32; ++j) {
        sp += bp[(size_t)j * N_TOK];
        sn += bn[(size_t)j * N_TOK];
    }
    __shared__ float shp[128], shn[128];
    if (jh) { shp[t & 127] = sp; shn[t & 127] = sn; }
    __syncthreads();
    float sumV = 0.f, sumA = 0.f, cnt = 0.f;
    if (!jh) {
        const float p = sp + shp[t];
        const float n = sn + shn[t];
        const float loss = -logf((p + EPS) / (p + n + EPS));
        sumA = loss;
        if (p > 0.f) { sumV = loss; cnt = 1.f; }
    }
#pragma unroll
    for (int m = 1; m <= 32; m <<= 1) {
        sumV += __shfl_xor(sumV, m);
        sumA += __shfl_xor(sumA, m);
        cnt += __shfl_xor(cnt, m);
    }
    __shared__ float wv[4], wa[4], wn[4];
    if ((t & 63) == 0) { wv[t >> 6] = sumV; wa[t >> 6] = sumA; wn[t >> 6] = cnt; }
    __syncthreads();
    if (t == 0) {
        atomicAdd(&acc[0], wv[0] + wv[1] + wv[2] + wv[3]);
        atomicAdd(&acc[1], wa[0] + wa[1] + wa[2] + wa[3]);
        atomicAdd(&acc[2], wn[0] + wn[1] + wn[2] + wn[3]);
    }
}

__global__ __launch_bounds__(64) void k_last(const float* __restrict__ acc,
                                             float* __restrict__ out) {
    if (threadIdx.x == 0) {
        const float nv = acc[2];
        out[0] = (nv > 0.f) ? (acc[0] / fmaxf(nv, 1.f)) : (acc[1] / (float)N_TOK);
    }
}

// ---------------------------------------------------------------- launch
extern "C" void kernel_launch(void* const* d_in, const int* in_sizes, int n_in,
                              void* d_out, int out_size, void* d_ws, size_t ws_size,
                              hipStream_t stream) {
    (void)in_sizes; (void)n_in; (void)out_size; (void)ws_size;
    const float* feats = (const float*)d_in[0];
    const int* did = (const int*)d_in[1];
    const int* iid = (const int*)d_in[2];
    char* ws = (char*)d_ws;
    char* Pq = ws + OFF_P;
    float* partP = (float*)(ws + OFF_PP);
    float* partN = (float*)(ws + OFF_PN);
    unsigned int* hist = (unsigned int*)(ws + OFF_HIST);
    float* thrp = (float*)(ws + OFF_THR);
    float* accum = (float*)(ws + OFF_THR + 16);

    k_prep<<<N_TOK / 4, 256, 0, stream>>>(feats, (unsigned int*)Pq, hist, accum);
    k_hist<<<65, 512, 0, stream>>>(Pq, did, hist);
    k_thr<<<1, 1024, 0, stream>>>(hist, thrp);
    k_main<<<64 * 65 / 2, 512, 0, stream>>>(Pq, did, iid, thrp, partP, partN);
    k_reduce<<<64, 256, 0, stream>>>(partP, partN, accum);
    k_last<<<1, 64, 0, stream>>>(accum, (float*)d_out);
}